// Round 17
// baseline (362.511 us; speedup 1.0000x reference)
//
#include <hip/hip_runtime.h>

// Scaled-dot-product attention, bs=4, h=16, S=2048, D=64, f32 in/out.
// Outputs O [64,2048,64] and P=attn_weights [64,2048,2048] (f32, 1.07 GB write).
// Confirmed levers: full-128B-line stores (R7 +13%); nt full-line stores
// bypassing L2 write-allocate (R10 +25%); store-duty widening via tile
// chaining (R14 +13%, duty 1/2 -> 2/3).
// Nulls: all scheduling/latency/transaction/page models (R5/6/9/12/13/15/16).
// R17: chain T=4 tiles/wave -> duty 4/5. Phases:
//   [p1A][p2A+p1B][p2B+p1C][p2C+p1D][p2D], K regs shared in fused phases.
// R14's exact proven loop bodies (j-step 32, direct loads, stores last).
// Tradeoff: 1024 waves (1/SIMD) instead of 2048 -- occupancy evidence (R11,
// fillBuffer at 10% occ) says store throughput survives low wave count.

#define S_LEN 2048
#define DH 64
#define NHEADS 64  // bs*h

typedef short short8 __attribute__((ext_vector_type(8)));   // 8 x bf16
typedef float f32x4 __attribute__((ext_vector_type(4)));
typedef float f32x16 __attribute__((ext_vector_type(16)));
typedef unsigned short u16;

__device__ __forceinline__ u16 f2bf(float f) {
  union { float f; unsigned u; } x;
  x.f = f;
  unsigned r = x.u + 0x7fffu + ((x.u >> 16) & 1u);  // RNE
  return (u16)(r >> 16);
}

__device__ __forceinline__ unsigned pkbf(float a, float b) {
  return (unsigned)f2bf(a) | ((unsigned)f2bf(b) << 16);
}

// v_permlane32_swap_b32: new a[32+i]=old b[i]; new b[i]=old a[32+i]
__device__ __forceinline__ void plswap(unsigned& a, unsigned& b) {
  asm("v_permlane32_swap_b32 %0, %1" : "+v"(a), "+v"(b));
}

__device__ __forceinline__ f32x16 qk4(short8 k0, short8 k1, short8 k2, short8 k3,
                                      short8 w0, short8 w1, short8 w2, short8 w3) {
  f32x16 s = {};
  s = __builtin_amdgcn_mfma_f32_32x32x16_bf16(k0, w0, s, 0, 0, 0);
  s = __builtin_amdgcn_mfma_f32_32x32x16_bf16(k1, w1, s, 0, 0, 0);
  s = __builtin_amdgcn_mfma_f32_32x32x16_bf16(k2, w2, s, 0, 0, 0);
  s = __builtin_amdgcn_mfma_f32_32x32x16_bf16(k3, w3, s, 0, 0, 0);
  return s;
}

// T12 redistribute: D-layout p[16] -> two A-frags (k = hi*8+i contiguous j)
__device__ __forceinline__ void packPA(const float* p, short8& f0, short8& f1) {
  unsigned A0 = pkbf(p[0], p[1]),   A1 = pkbf(p[2], p[3]);
  unsigned B0 = pkbf(p[4], p[5]),   B1 = pkbf(p[6], p[7]);
  plswap(A0, B0);
  plswap(A1, B1);
  unsigned C0 = pkbf(p[8], p[9]),   C1 = pkbf(p[10], p[11]);
  unsigned D0 = pkbf(p[12], p[13]), D1 = pkbf(p[14], p[15]);
  plswap(C0, D0);
  plswap(C1, D1);
  union { unsigned w[4]; short8 v; } u0 = {{A0, A1, B0, B1}};
  union { unsigned w[4]; short8 v; } u1 = {{C0, C1, D0, D1}};
  f0 = u0.v;
  f1 = u1.v;
}

// ---- pre-pass: Q * scale -> bf16, same layout ----
__global__ __launch_bounds__(256) void cvt_scale_k(const float* __restrict__ in,
                                                   u16* __restrict__ out,
                                                   float scale, int n4) {
  int i = blockIdx.x * 256 + threadIdx.x;
  if (i >= n4) return;
  float4 v = ((const float4*)in)[i];
  union { u16 s[4]; unsigned long long ll; } o;
  o.s[0] = f2bf(v.x * scale); o.s[1] = f2bf(v.y * scale);
  o.s[2] = f2bf(v.z * scale); o.s[3] = f2bf(v.w * scale);
  ((unsigned long long*)out)[i] = o.ll;
}

// ---- pre-pass: per-head transpose [R][C] f32 -> [C][R] bf16 ----
__global__ __launch_bounds__(256) void transpose_cvt_k(const float* __restrict__ in,
                                                       u16* __restrict__ out,
                                                       int R, int C) {
  __shared__ float tile[64][65];
  const int tilesC = C >> 6;
  const int tilesPerHead = (R >> 6) * tilesC;
  int hb = blockIdx.x;
  int head = hb / tilesPerHead;
  int t = hb - head * tilesPerHead;
  int tr = t / tilesC, tc = t - tr * tilesC;
  const float* ip = in + (size_t)head * R * C + (size_t)tr * 64 * C + (size_t)tc * 64;
  u16* op = out + (size_t)head * R * C + (size_t)tc * 64 * R + (size_t)tr * 64;
  int c = threadIdx.x & 63, r0 = threadIdx.x >> 6;
#pragma unroll
  for (int k = 0; k < 16; ++k) {
    int r = (k << 2) + r0;
    tile[r][c] = ip[(size_t)r * C + c];
  }
  __syncthreads();
#pragma unroll
  for (int k = 0; k < 16; ++k) {
    int orow = (k << 2) + r0;
    op[(size_t)orow * R + c] = f2bf(tile[c][orow]);
  }
}

// ---- attention helpers (R14 proven bodies) ----

// pass1: full-row softmax denominator for one 32-row tile -> 1/l
__device__ __forceinline__ float pass1_full(const u16* kp, short8 q0f, short8 q1f,
                                            short8 q2f, short8 q3f) {
  float l0 = 0.f, l1 = 0.f, l2 = 0.f, l3 = 0.f;
  for (int j0 = 0; j0 < S_LEN; j0 += 32) {
    const u16* kb = kp + (size_t)j0 * DH;
    short8 k0 = *(const short8*)(kb);
    short8 k1 = *(const short8*)(kb + 16);
    short8 k2 = *(const short8*)(kb + 32);
    short8 k3 = *(const short8*)(kb + 48);
    f32x16 s = qk4(k0, k1, k2, k3, q0f, q1f, q2f, q3f);
#pragma unroll
    for (int r = 0; r < 16; r += 4) {
      l0 += __expf(s[r]);
      l1 += __expf(s[r + 1]);
      l2 += __expf(s[r + 2]);
      l3 += __expf(s[r + 3]);
    }
  }
  float ls = (l0 + l1) + (l2 + l3);
  ls += __shfl_xor(ls, 32);  // hi/lo halves hold disjoint j subsets
  return 1.f / ls;
}

// fused: pass2(cur tile) + pass1(next tile) sharing K regs (R14 phase-2 body)
__device__ __forceinline__ void fused_phase(
    const u16* kp, const u16* vp, float* tw, float* pbase,
    short8 qa0, short8 qa1, short8 qa2, short8 qa3, float rl,
    short8 qb0, short8 qb1, short8 qb2, short8 qb3,
    f32x16& oa, f32x16& ob, float& lnext,
    int q, int hi, int rq, int rc) {
  float lb0 = 0.f, lb1 = 0.f, lb2 = 0.f, lb3 = 0.f;
  for (int j0 = 0; j0 < S_LEN; j0 += 32) {
    const u16* kb = kp + (size_t)j0 * DH;
    short8 k0 = *(const short8*)(kb);
    short8 k1 = *(const short8*)(kb + 16);
    short8 k2 = *(const short8*)(kb + 32);
    short8 k3 = *(const short8*)(kb + 48);
    const u16* vj = vp + j0;
    short8 v0 = *(const short8*)(vj);
    short8 v1 = *(const short8*)(vj + 16);
    short8 v2 = *(const short8*)(vj + 32 * S_LEN);
    short8 v3 = *(const short8*)(vj + 32 * S_LEN + 16);

    f32x16 s = qk4(k0, k1, k2, k3, qa0, qa1, qa2, qa3);
    float p[16];
#pragma unroll
    for (int r = 0; r < 16; ++r) p[r] = __expf(s[r]) * rl;

    // LDS transpose write (chunk-XOR swizzle, ~4-way)
#pragma unroll
    for (int g = 0; g < 4; ++g) {
      int phys = (2 * g + hi) ^ (q & 7);
      f32x4 w = {p[4 * g], p[4 * g + 1], p[4 * g + 2], p[4 * g + 3]};
      *(f32x4*)&tw[q * 32 + phys * 4] = w;
    }

    short8 pa0, pa1;
    packPA(p, pa0, pa1);
    oa = __builtin_amdgcn_mfma_f32_32x32x16_bf16(pa0, v0, oa, 0, 0, 0);
    oa = __builtin_amdgcn_mfma_f32_32x32x16_bf16(pa1, v1, oa, 0, 0, 0);
    ob = __builtin_amdgcn_mfma_f32_32x32x16_bf16(pa0, v2, ob, 0, 0, 0);
    ob = __builtin_amdgcn_mfma_f32_32x32x16_bf16(pa1, v3, ob, 0, 0, 0);

    // pass1(next) on the SAME K registers
    f32x16 sb = qk4(k0, k1, k2, k3, qb0, qb1, qb2, qb3);
#pragma unroll
    for (int r = 0; r < 16; r += 4) {
      lb0 += __expf(sb[r]);
      lb1 += __expf(sb[r + 1]);
      lb2 += __expf(sb[r + 2]);
      lb3 += __expf(sb[r + 3]);
    }

    // full-line nt P stores -- LAST vmem of the body
    float* ps = pbase + j0;
#pragma unroll
    for (int g = 0; g < 4; ++g) {
      int qi = 8 * g + rq;
      int phys = rc ^ (qi & 7);
      f32x4 v = *(const f32x4*)&tw[qi * 32 + phys * 4];
      __builtin_nontemporal_store(v, (f32x4*)(ps + (size_t)qi * S_LEN + rc * 4));
    }
  }
  float ls = (lb0 + lb1) + (lb2 + lb3);
  ls += __shfl_xor(ls, 32);
  lnext = 1.f / ls;
}

// pass2 only (final tile, R14 phase-3 body)
__device__ __forceinline__ void pass2_only(
    const u16* kp, const u16* vp, float* tw, float* pbase,
    short8 qa0, short8 qa1, short8 qa2, short8 qa3, float rl,
    f32x16& oa, f32x16& ob, int q, int hi, int rq, int rc) {
  for (int j0 = 0; j0 < S_LEN; j0 += 32) {
    const u16* kb = kp + (size_t)j0 * DH;
    short8 k0 = *(const short8*)(kb);
    short8 k1 = *(const short8*)(kb + 16);
    short8 k2 = *(const short8*)(kb + 32);
    short8 k3 = *(const short8*)(kb + 48);
    const u16* vj = vp + j0;
    short8 v0 = *(const short8*)(vj);
    short8 v1 = *(const short8*)(vj + 16);
    short8 v2 = *(const short8*)(vj + 32 * S_LEN);
    short8 v3 = *(const short8*)(vj + 32 * S_LEN + 16);

    f32x16 s = qk4(k0, k1, k2, k3, qa0, qa1, qa2, qa3);
    float p[16];
#pragma unroll
    for (int r = 0; r < 16; ++r) p[r] = __expf(s[r]) * rl;

#pragma unroll
    for (int g = 0; g < 4; ++g) {
      int phys = (2 * g + hi) ^ (q & 7);
      f32x4 w = {p[4 * g], p[4 * g + 1], p[4 * g + 2], p[4 * g + 3]};
      *(f32x4*)&tw[q * 32 + phys * 4] = w;
    }

    short8 pa0, pa1;
    packPA(p, pa0, pa1);
    oa = __builtin_amdgcn_mfma_f32_32x32x16_bf16(pa0, v0, oa, 0, 0, 0);
    oa = __builtin_amdgcn_mfma_f32_32x32x16_bf16(pa1, v1, oa, 0, 0, 0);
    ob = __builtin_amdgcn_mfma_f32_32x32x16_bf16(pa0, v2, ob, 0, 0, 0);
    ob = __builtin_amdgcn_mfma_f32_32x32x16_bf16(pa1, v3, ob, 0, 0, 0);

    float* ps = pbase + j0;
#pragma unroll
    for (int g = 0; g < 4; ++g) {
      int qi = 8 * g + rq;
      int phys = rc ^ (qi & 7);
      f32x4 v = *(const f32x4*)&tw[qi * 32 + phys * 4];
      __builtin_nontemporal_store(v, (f32x4*)(ps + (size_t)qi * S_LEN + rc * 4));
    }
  }
}

// O epilogue: LDS transpose -> full-line nt stores
__device__ __forceinline__ void o_epilogue(float* tw, const f32x16& oa,
                                           const f32x16& ob, float* og,
                                           int q, int hi, int rq, int rc) {
#pragma unroll
  for (int r = 0; r < 16; ++r) {
    int qi = (r & 3) + 8 * (r >> 2) + 4 * hi;
    tw[qi * 32 + q] = oa[r];   // bank = q -> conflict-free
  }
#pragma unroll
  for (int g = 0; g < 4; ++g) {
    int qi = 8 * g + rq;
    f32x4 v = *(const f32x4*)&tw[qi * 32 + rc * 4];
    __builtin_nontemporal_store(v, (f32x4*)(og + (size_t)qi * DH + rc * 4));
  }
#pragma unroll
  for (int r = 0; r < 16; ++r) {
    int qi = (r & 3) + 8 * (r >> 2) + 4 * hi;
    tw[qi * 32 + q] = ob[r];
  }
#pragma unroll
  for (int g = 0; g < 4; ++g) {
    int qi = 8 * g + rq;
    f32x4 v = *(const f32x4*)&tw[qi * 32 + rc * 4];
    __builtin_nontemporal_store(v, (f32x4*)(og + (size_t)qi * DH + 32 + rc * 4));
  }
}

// ---- fused attention: T=4 tile chain per wave, duty 4/5 ----
// Layouts (bf16): Qb [h][s][d] (pre-scaled), Kn [h][s][d], Vt [h][d][s].
// 512 blocks x 2 waves; wave wv owns tiles t=0..3 at q0 = rblk*256 + t*64 + wv*32.
__global__ __launch_bounds__(128, 1) void attn_k(const u16* __restrict__ Qb,
                                                 const u16* __restrict__ Kn,
                                                 const u16* __restrict__ Vt,
                                                 float* __restrict__ Og,
                                                 float* __restrict__ Pg) {
  __shared__ float tile[2][32 * 32];
  int bid = blockIdx.x;
  // bijective XCD swizzle: 512 blocks, XCD x gets heads 8x..8x+7
  int work = ((bid & 7) << 6) | (bid >> 3);
  int head = work >> 3;
  int rblk = work & 7;
  int lane = threadIdx.x & 63;
  int wv = threadIdx.x >> 6;
  int q = lane & 31;
  int hi = lane >> 5;
  float* tw = tile[wv];
  int rq = lane >> 3;
  int rc = lane & 7;

  int base = (rblk << 8) + (wv << 5);
  int q0A = base, q0B = base + 64, q0C = base + 128, q0D = base + 192;

  const u16* qh = Qb + (size_t)head * S_LEN * DH;
  const u16* qpA = qh + (size_t)(q0A + q) * DH + hi * 8;
  short8 qa0 = *(const short8*)(qpA),      qa1 = *(const short8*)(qpA + 16);
  short8 qa2 = *(const short8*)(qpA + 32), qa3 = *(const short8*)(qpA + 48);
  const u16* qpB = qh + (size_t)(q0B + q) * DH + hi * 8;
  short8 qb0 = *(const short8*)(qpB),      qb1 = *(const short8*)(qpB + 16);
  short8 qb2 = *(const short8*)(qpB + 32), qb3 = *(const short8*)(qpB + 48);
  const u16* qpC = qh + (size_t)(q0C + q) * DH + hi * 8;
  short8 qc0 = *(const short8*)(qpC),      qc1 = *(const short8*)(qpC + 16);
  short8 qc2 = *(const short8*)(qpC + 32), qc3 = *(const short8*)(qpC + 48);
  const u16* qpD = qh + (size_t)(q0D + q) * DH + hi * 8;
  short8 qd0 = *(const short8*)(qpD),      qd1 = *(const short8*)(qpD + 16);
  short8 qd2 = *(const short8*)(qpD + 32), qd3 = *(const short8*)(qpD + 48);

  const u16* kp = Kn + (size_t)head * S_LEN * DH + (size_t)q * DH + hi * 8;
  const u16* vp = Vt + (size_t)head * DH * S_LEN + (size_t)q * S_LEN + hi * 8;
  float* ph = Pg + (size_t)head * S_LEN * S_LEN;
  float* oh = Og + (size_t)head * S_LEN * DH;

  // phase 0: p1(A)
  float rlA = pass1_full(kp, qa0, qa1, qa2, qa3);

  // phase 1: p2(A) + p1(B)
  f32x16 oa = {}, ob = {};
  float rlB;
  fused_phase(kp, vp, tw, ph + (size_t)q0A * S_LEN, qa0, qa1, qa2, qa3, rlA,
              qb0, qb1, qb2, qb3, oa, ob, rlB, q, hi, rq, rc);
  o_epilogue(tw, oa, ob, oh + (size_t)q0A * DH, q, hi, rq, rc);

  // phase 2: p2(B) + p1(C)
  oa = (f32x16){}; ob = (f32x16){};
  float rlC;
  fused_phase(kp, vp, tw, ph + (size_t)q0B * S_LEN, qb0, qb1, qb2, qb3, rlB,
              qc0, qc1, qc2, qc3, oa, ob, rlC, q, hi, rq, rc);
  o_epilogue(tw, oa, ob, oh + (size_t)q0B * DH, q, hi, rq, rc);

  // phase 3: p2(C) + p1(D)
  oa = (f32x16){}; ob = (f32x16){};
  float rlD;
  fused_phase(kp, vp, tw, ph + (size_t)q0C * S_LEN, qc0, qc1, qc2, qc3, rlC,
              qd0, qd1, qd2, qd3, oa, ob, rlD, q, hi, rq, rc);
  o_epilogue(tw, oa, ob, oh + (size_t)q0C * DH, q, hi, rq, rc);

  // phase 4: p2(D)
  oa = (f32x16){}; ob = (f32x16){};
  pass2_only(kp, vp, tw, ph + (size_t)q0D * S_LEN, qd0, qd1, qd2, qd3, rlD,
             oa, ob, q, hi, rq, rc);
  o_epilogue(tw, oa, ob, oh + (size_t)q0D * DH, q, hi, rq, rc);
}

extern "C" void kernel_launch(void* const* d_in, const int* in_sizes, int n_in,
                              void* d_out, int out_size, void* d_ws, size_t ws_size,
                              hipStream_t stream) {
  const float* q = (const float*)d_in[0];
  const float* k = (const float*)d_in[1];  // [b,h,d,s]
  const float* v = (const float*)d_in[2];  // [b,h,s,d]
  float* Og = (float*)d_out;
  float* Pg = Og + (size_t)NHEADS * S_LEN * DH;

  const size_t elems = (size_t)NHEADS * S_LEN * DH;  // 8,388,608
  u16* Qb = (u16*)d_ws;           // bf16 [h][s][d], pre-scaled
  u16* Kn = Qb + elems;           // bf16 [h][s][d]
  u16* Vt = Kn + elems;           // bf16 [h][d][s]

  int n4 = (int)(elems / 4);
  cvt_scale_k<<<n4 / 256, 256, 0, stream>>>(q, Qb, 0.125f, n4);
  transpose_cvt_k<<<NHEADS * (S_LEN / 64), 256, 0, stream>>>(k, Kn, DH, S_LEN);
  transpose_cvt_k<<<NHEADS * (S_LEN / 64), 256, 0, stream>>>(v, Vt, S_LEN, DH);
  attn_k<<<NHEADS * (S_LEN / 256), 128, 0, stream>>>(Qb, Kn, Vt, Og, Pg);
}

// Round 18
// 346.467 us; speedup vs baseline: 1.0463x; 1.0463x over previous
//
#include <hip/hip_runtime.h>

// Scaled-dot-product attention, bs=4, h=16, S=2048, D=64, f32 in/out.
// Outputs O [64,2048,64] and P=attn_weights [64,2048,2048] (f32, 1.07 GB write).
// FINAL STRUCTURE (best = R14, 350 us):
//   prep_k (merged single launch): Q*scale->bf16, K^T->bf16, V^T->bf16
//   attn_k: 2-tile/wave chain [p1A][p2A+p1B][p2B], swapped-QK^T 32x32,
//           LDS-transposed FULL-LINE nt stores for P and O.
// Confirmed levers: full-128B-line stores (R7 +13%); nt stores bypassing L2
// write-allocate (R10 +25%); T=2 duty widening (R14 +13%).
// Closed nulls: reg prefetch (R5/6/15), wave specialization (R13 -16%),
// store bursts (R9/R12), occupancy 4v3 (R11), deferred/batched stores (R16),
// T=4 chain (R17 -3.5%). In-window store rate ~4.4 TB/s with interleaved
// compute is the practical ceiling of this structure.

#define S_LEN 2048
#define DH 64
#define NHEADS 64  // bs*h

typedef short short8 __attribute__((ext_vector_type(8)));   // 8 x bf16
typedef float f32x4 __attribute__((ext_vector_type(4)));
typedef float f32x16 __attribute__((ext_vector_type(16)));
typedef unsigned short u16;

__device__ __forceinline__ u16 f2bf(float f) {
  union { float f; unsigned u; } x;
  x.f = f;
  unsigned r = x.u + 0x7fffu + ((x.u >> 16) & 1u);  // RNE
  return (u16)(r >> 16);
}

__device__ __forceinline__ unsigned pkbf(float a, float b) {
  return (unsigned)f2bf(a) | ((unsigned)f2bf(b) << 16);  // a -> low, b -> high
}

// v_permlane32_swap_b32: new a[32+i]=old b[i]; new b[i]=old a[32+i]
__device__ __forceinline__ void plswap(unsigned& a, unsigned& b) {
  asm("v_permlane32_swap_b32 %0, %1" : "+v"(a), "+v"(b));
}

// ---- merged pre-pass: one launch, block-range dispatch ----
// blocks [0, 8192)            : Q * scale -> bf16 (same layout)
// blocks [8192, 10240)        : K [h][d][s] -> Kn [h][s][d] bf16
// blocks [10240, 12288)       : V [h][s][d] -> Vt [h][d][s] bf16
__global__ __launch_bounds__(256) void prep_k(const float* __restrict__ qin,
                                              const float* __restrict__ kin,
                                              const float* __restrict__ vin,
                                              u16* __restrict__ Qb,
                                              u16* __restrict__ Kn,
                                              u16* __restrict__ Vt) {
  __shared__ float tile[64][65];
  int b = blockIdx.x;
  if (b < 8192) {
    int i = b * 256 + threadIdx.x;
    float4 v = ((const float4*)qin)[i];
    union { u16 s[4]; unsigned long long ll; } o;
    o.s[0] = f2bf(v.x * 0.125f); o.s[1] = f2bf(v.y * 0.125f);
    o.s[2] = f2bf(v.z * 0.125f); o.s[3] = f2bf(v.w * 0.125f);
    ((unsigned long long*)Qb)[i] = o.ll;
    return;
  }
  const float* in;
  u16* out;
  int R, C, hb;
  if (b < 10240) {  // K: [h][64][2048] -> [h][2048][64]
    in = kin; out = Kn; R = DH; C = S_LEN; hb = b - 8192;
  } else {          // V: [h][2048][64] -> [h][64][2048]
    in = vin; out = Vt; R = S_LEN; C = DH; hb = b - 10240;
  }
  const int tilesC = C >> 6;
  const int tilesPerHead = (R >> 6) * tilesC;
  int head = hb / tilesPerHead;
  int t = hb - head * tilesPerHead;
  int tr = t / tilesC, tc = t - tr * tilesC;
  const float* ip = in + (size_t)head * R * C + (size_t)tr * 64 * C + (size_t)tc * 64;
  u16* op = out + (size_t)head * R * C + (size_t)tc * 64 * R + (size_t)tr * 64;
  int c = threadIdx.x & 63, r0 = threadIdx.x >> 6;
#pragma unroll
  for (int k = 0; k < 16; ++k) {
    int r = (k << 2) + r0;
    tile[r][c] = ip[(size_t)r * C + c];
  }
  __syncthreads();
#pragma unroll
  for (int k = 0; k < 16; ++k) {
    int orow = (k << 2) + r0;
    op[(size_t)orow * R + c] = f2bf(tile[c][orow]);
  }
}

// ---- fused attention, 2-tile/wave pipeline, nt full-line stores (R14) ----
// Layouts (bf16): Qb [h][s][d] (pre-scaled), Kn [h][s][d], Vt [h][d][s].
// Block = 4 waves; wave owns tiles A (q0) and B (q0+128), 32 rows each.
// mfma_f32_32x32x16_bf16:  A row=lane&31, k=(lane>>5)*8+i (8 contig)
//                          B col=lane&31, k=(lane>>5)*8+i
//                          D col=lane&31, row=(r&3)+8*(r>>2)+4*(lane>>5)
__global__ __launch_bounds__(256, 2) void attn_k(const u16* __restrict__ Qb,
                                                 const u16* __restrict__ Kn,
                                                 const u16* __restrict__ Vt,
                                                 float* __restrict__ Og,
                                                 float* __restrict__ Pg) {
  // per-wave 32x32 f32 transpose tile; row stride 32 floats (128 B).
  __shared__ float tile[4][32 * 32];
  int bid = blockIdx.x;
  // bijective XCD swizzle: 512 blocks, XCD x gets heads 8x..8x+7
  int work = ((bid & 7) << 6) | (bid >> 3);
  int head = work >> 3;
  int rblk = work & 7;                  // 8 row-blocks of 256 q-rows
  int lane = threadIdx.x & 63;
  int wv = threadIdx.x >> 6;
  int q = lane & 31;
  int hi = lane >> 5;
  int q0A = (rblk << 8) + (wv << 5);    // tile A rows
  int q0B = q0A + 128;                  // tile B rows
  float* tw = tile[wv];
  int rq = lane >> 3;   // 0..7: row-within-group for line stores
  int rc = lane & 7;    // 0..7: 16B chunk within the 128B line

  // Q fragments for both tiles, resident
  const u16* qpA = Qb + (size_t)(head * S_LEN + q0A + q) * DH + hi * 8;
  short8 qa0 = *(const short8*)(qpA);
  short8 qa1 = *(const short8*)(qpA + 16);
  short8 qa2 = *(const short8*)(qpA + 32);
  short8 qa3 = *(const short8*)(qpA + 48);
  const u16* qpB = Qb + (size_t)(head * S_LEN + q0B + q) * DH + hi * 8;
  short8 qb0 = *(const short8*)(qpB);
  short8 qb1 = *(const short8*)(qpB + 16);
  short8 qb2 = *(const short8*)(qpB + 32);
  short8 qb3 = *(const short8*)(qpB + 48);

  const u16* kp = Kn + (size_t)head * S_LEN * DH + (size_t)q * DH + hi * 8;
  const u16* vp = Vt + (size_t)head * DH * S_LEN + (size_t)q * S_LEN + hi * 8;

  // ---- phase 1: lA = sum_j exp(sA) ----
  float la0 = 0.f, la1 = 0.f, la2 = 0.f, la3 = 0.f;
  for (int j0 = 0; j0 < S_LEN; j0 += 32) {
    const u16* kb = kp + (size_t)j0 * DH;
    short8 k0 = *(const short8*)(kb);
    short8 k1 = *(const short8*)(kb + 16);
    short8 k2 = *(const short8*)(kb + 32);
    short8 k3 = *(const short8*)(kb + 48);
    f32x16 s = {};
    s = __builtin_amdgcn_mfma_f32_32x32x16_bf16(k0, qa0, s, 0, 0, 0);
    s = __builtin_amdgcn_mfma_f32_32x32x16_bf16(k1, qa1, s, 0, 0, 0);
    s = __builtin_amdgcn_mfma_f32_32x32x16_bf16(k2, qa2, s, 0, 0, 0);
    s = __builtin_amdgcn_mfma_f32_32x32x16_bf16(k3, qa3, s, 0, 0, 0);
#pragma unroll
    for (int r = 0; r < 16; r += 4) {
      la0 += __expf(s[r]);
      la1 += __expf(s[r + 1]);
      la2 += __expf(s[r + 2]);
      la3 += __expf(s[r + 3]);
    }
  }
  float lsA = (la0 + la1) + (la2 + la3);
  lsA += __shfl_xor(lsA, 32);
  float rlA = 1.f / lsA;

  // ---- phase 2: pass2(A) + pass1(B), sharing K tiles ----
  f32x16 oa = {}, ob = {};
  float lb0 = 0.f, lb1 = 0.f, lb2 = 0.f, lb3 = 0.f;
  float* pbA = Pg + (size_t)(head * S_LEN + q0A) * S_LEN;

  for (int j0 = 0; j0 < S_LEN; j0 += 32) {
    const u16* kb = kp + (size_t)j0 * DH;
    short8 k0 = *(const short8*)(kb);
    short8 k1 = *(const short8*)(kb + 16);
    short8 k2 = *(const short8*)(kb + 32);
    short8 k3 = *(const short8*)(kb + 48);
    const u16* vj = vp + j0;
    short8 v0 = *(const short8*)(vj);
    short8 v1 = *(const short8*)(vj + 16);
    short8 v2 = *(const short8*)(vj + 32 * S_LEN);
    short8 v3 = *(const short8*)(vj + 32 * S_LEN + 16);

    f32x16 s = {};
    s = __builtin_amdgcn_mfma_f32_32x32x16_bf16(k0, qa0, s, 0, 0, 0);
    s = __builtin_amdgcn_mfma_f32_32x32x16_bf16(k1, qa1, s, 0, 0, 0);
    s = __builtin_amdgcn_mfma_f32_32x32x16_bf16(k2, qa2, s, 0, 0, 0);
    s = __builtin_amdgcn_mfma_f32_32x32x16_bf16(k3, qa3, s, 0, 0, 0);

    float p[16];
#pragma unroll
    for (int r = 0; r < 16; ++r) p[r] = __expf(s[r]) * rlA;

    // LDS transpose write (chunk-XOR swizzle, ~4-way)
#pragma unroll
    for (int g = 0; g < 4; ++g) {
      int phys = (2 * g + hi) ^ (q & 7);
      f32x4 w = {p[4 * g], p[4 * g + 1], p[4 * g + 2], p[4 * g + 3]};
      *(f32x4*)&tw[q * 32 + phys * 4] = w;
    }

    // T12 redistribute: D-layout -> A-frag
    unsigned A0 = pkbf(p[0], p[1]),   A1 = pkbf(p[2], p[3]);
    unsigned B0 = pkbf(p[4], p[5]),   B1 = pkbf(p[6], p[7]);
    plswap(A0, B0);
    plswap(A1, B1);
    unsigned C0 = pkbf(p[8], p[9]),   C1 = pkbf(p[10], p[11]);
    unsigned D0 = pkbf(p[12], p[13]), D1 = pkbf(p[14], p[15]);
    plswap(C0, D0);
    plswap(C1, D1);
    union { unsigned w[4]; short8 v; } pa0u = {{A0, A1, B0, B1}};
    union { unsigned w[4]; short8 v; } pa1u = {{C0, C1, D0, D1}};

    oa = __builtin_amdgcn_mfma_f32_32x32x16_bf16(pa0u.v, v0, oa, 0, 0, 0);
    oa = __builtin_amdgcn_mfma_f32_32x32x16_bf16(pa1u.v, v1, oa, 0, 0, 0);
    ob = __builtin_amdgcn_mfma_f32_32x32x16_bf16(pa0u.v, v2, ob, 0, 0, 0);
    ob = __builtin_amdgcn_mfma_f32_32x32x16_bf16(pa1u.v, v3, ob, 0, 0, 0);

    // pass1(B) on the SAME K registers
    f32x16 sb = {};
    sb = __builtin_amdgcn_mfma_f32_32x32x16_bf16(k0, qb0, sb, 0, 0, 0);
    sb = __builtin_amdgcn_mfma_f32_32x32x16_bf16(k1, qb1, sb, 0, 0, 0);
    sb = __builtin_amdgcn_mfma_f32_32x32x16_bf16(k2, qb2, sb, 0, 0, 0);
    sb = __builtin_amdgcn_mfma_f32_32x32x16_bf16(k3, qb3, sb, 0, 0, 0);
#pragma unroll
    for (int r = 0; r < 16; r += 4) {
      lb0 += __expf(sb[r]);
      lb1 += __expf(sb[r + 1]);
      lb2 += __expf(sb[r + 2]);
      lb3 += __expf(sb[r + 3]);
    }

    // full-line nt P_A stores -- LAST vmem of the body
    float* ps = pbA + j0;
#pragma unroll
    for (int g = 0; g < 4; ++g) {
      int qi = 8 * g + rq;
      int phys = rc ^ (qi & 7);
      f32x4 v = *(const f32x4*)&tw[qi * 32 + phys * 4];
      __builtin_nontemporal_store(v, (f32x4*)(ps + (size_t)qi * S_LEN + rc * 4));
    }
  }

  // ---- O_A epilogue ----
  float* ogA = Og + (size_t)(head * S_LEN + q0A) * DH;
#pragma unroll
  for (int r = 0; r < 16; ++r) {
    int qi = (r & 3) + 8 * (r >> 2) + 4 * hi;
    tw[qi * 32 + q] = oa[r];
  }
#pragma unroll
  for (int g = 0; g < 4; ++g) {
    int qi = 8 * g + rq;
    f32x4 v = *(const f32x4*)&tw[qi * 32 + rc * 4];
    __builtin_nontemporal_store(v, (f32x4*)(ogA + (size_t)qi * DH + rc * 4));
  }
#pragma unroll
  for (int r = 0; r < 16; ++r) {
    int qi = (r & 3) + 8 * (r >> 2) + 4 * hi;
    tw[qi * 32 + q] = ob[r];
  }
#pragma unroll
  for (int g = 0; g < 4; ++g) {
    int qi = 8 * g + rq;
    f32x4 v = *(const f32x4*)&tw[qi * 32 + rc * 4];
    __builtin_nontemporal_store(v, (f32x4*)(ogA + (size_t)qi * DH + 32 + rc * 4));
  }

  float lsB = (lb0 + lb1) + (lb2 + lb3);
  lsB += __shfl_xor(lsB, 32);
  float rlB = 1.f / lsB;

  // ---- phase 3: pass2(B) ----
  oa = (f32x16){};
  ob = (f32x16){};
  float* pbB = Pg + (size_t)(head * S_LEN + q0B) * S_LEN;

  for (int j0 = 0; j0 < S_LEN; j0 += 32) {
    const u16* kb = kp + (size_t)j0 * DH;
    short8 k0 = *(const short8*)(kb);
    short8 k1 = *(const short8*)(kb + 16);
    short8 k2 = *(const short8*)(kb + 32);
    short8 k3 = *(const short8*)(kb + 48);
    const u16* vj = vp + j0;
    short8 v0 = *(const short8*)(vj);
    short8 v1 = *(const short8*)(vj + 16);
    short8 v2 = *(const short8*)(vj + 32 * S_LEN);
    short8 v3 = *(const short8*)(vj + 32 * S_LEN + 16);

    f32x16 s = {};
    s = __builtin_amdgcn_mfma_f32_32x32x16_bf16(k0, qb0, s, 0, 0, 0);
    s = __builtin_amdgcn_mfma_f32_32x32x16_bf16(k1, qb1, s, 0, 0, 0);
    s = __builtin_amdgcn_mfma_f32_32x32x16_bf16(k2, qb2, s, 0, 0, 0);
    s = __builtin_amdgcn_mfma_f32_32x32x16_bf16(k3, qb3, s, 0, 0, 0);

    float p[16];
#pragma unroll
    for (int r = 0; r < 16; ++r) p[r] = __expf(s[r]) * rlB;

#pragma unroll
    for (int g = 0; g < 4; ++g) {
      int phys = (2 * g + hi) ^ (q & 7);
      f32x4 w = {p[4 * g], p[4 * g + 1], p[4 * g + 2], p[4 * g + 3]};
      *(f32x4*)&tw[q * 32 + phys * 4] = w;
    }

    unsigned A0 = pkbf(p[0], p[1]),   A1 = pkbf(p[2], p[3]);
    unsigned B0 = pkbf(p[4], p[5]),   B1 = pkbf(p[6], p[7]);
    plswap(A0, B0);
    plswap(A1, B1);
    unsigned C0 = pkbf(p[8], p[9]),   C1 = pkbf(p[10], p[11]);
    unsigned D0 = pkbf(p[12], p[13]), D1 = pkbf(p[14], p[15]);
    plswap(C0, D0);
    plswap(C1, D1);
    union { unsigned w[4]; short8 v; } pa0u = {{A0, A1, B0, B1}};
    union { unsigned w[4]; short8 v; } pa1u = {{C0, C1, D0, D1}};

    oa = __builtin_amdgcn_mfma_f32_32x32x16_bf16(pa0u.v, v0, oa, 0, 0, 0);
    oa = __builtin_amdgcn_mfma_f32_32x32x16_bf16(pa1u.v, v1, oa, 0, 0, 0);
    ob = __builtin_amdgcn_mfma_f32_32x32x16_bf16(pa0u.v, v2, ob, 0, 0, 0);
    ob = __builtin_amdgcn_mfma_f32_32x32x16_bf16(pa1u.v, v3, ob, 0, 0, 0);

    float* ps = pbB + j0;
#pragma unroll
    for (int g = 0; g < 4; ++g) {
      int qi = 8 * g + rq;
      int phys = rc ^ (qi & 7);
      f32x4 v = *(const f32x4*)&tw[qi * 32 + phys * 4];
      __builtin_nontemporal_store(v, (f32x4*)(ps + (size_t)qi * S_LEN + rc * 4));
    }
  }

  // ---- O_B epilogue ----
  float* ogB = Og + (size_t)(head * S_LEN + q0B) * DH;
#pragma unroll
  for (int r = 0; r < 16; ++r) {
    int qi = (r & 3) + 8 * (r >> 2) + 4 * hi;
    tw[qi * 32 + q] = oa[r];
  }
#pragma unroll
  for (int g = 0; g < 4; ++g) {
    int qi = 8 * g + rq;
    f32x4 v = *(const f32x4*)&tw[qi * 32 + rc * 4];
    __builtin_nontemporal_store(v, (f32x4*)(ogB + (size_t)qi * DH + rc * 4));
  }
#pragma unroll
  for (int r = 0; r < 16; ++r) {
    int qi = (r & 3) + 8 * (r >> 2) + 4 * hi;
    tw[qi * 32 + q] = ob[r];
  }
#pragma unroll
  for (int g = 0; g < 4; ++g) {
    int qi = 8 * g + rq;
    f32x4 v = *(const f32x4*)&tw[qi * 32 + rc * 4];
    __builtin_nontemporal_store(v, (f32x4*)(ogB + (size_t)qi * DH + 32 + rc * 4));
  }
}

extern "C" void kernel_launch(void* const* d_in, const int* in_sizes, int n_in,
                              void* d_out, int out_size, void* d_ws, size_t ws_size,
                              hipStream_t stream) {
  const float* q = (const float*)d_in[0];
  const float* k = (const float*)d_in[1];  // [b,h,d,s]
  const float* v = (const float*)d_in[2];  // [b,h,s,d]
  float* Og = (float*)d_out;
  float* Pg = Og + (size_t)NHEADS * S_LEN * DH;

  const size_t elems = (size_t)NHEADS * S_LEN * DH;  // 8,388,608
  u16* Qb = (u16*)d_ws;           // bf16 [h][s][d], pre-scaled
  u16* Kn = Qb + elems;           // bf16 [h][s][d]
  u16* Vt = Kn + elems;           // bf16 [h][d][s]

  // merged pre-pass: 8192 cvt + 2048 K-transpose + 2048 V-transpose blocks
  prep_k<<<12288, 256, 0, stream>>>(q, k, v, Qb, Kn, Vt);
  attn_k<<<NHEADS * (S_LEN / 256), 256, 0, stream>>>(Qb, Kn, Vt, Og, Pg);
}